// Round 5
// baseline (564.859 us; speedup 1.0000x reference)
//
#include <hip/hip_runtime.h>

#define NSAMP 2048
#define DIM 1024
#define NCLS 224
#define PERCLS 224
#define CH 16
#define KSL 128                    // k per k-group; block spans 2*KSL = 256 k
#define NSLICE 4                   // 4 block-slices (k-groups merged in-block)
#define TOPBLKS ((NSAMP / CH) * NSLICE)   // 512
#define BOTBLKS (NCLS * NSLICE)           // 896

struct Ws {
  int cls[NSAMP];
  int within[NSAMP];
  int order[NSAMP];
  int offsets[NCLS + 1];
  float top_part[NSLICE][NSAMP][NCLS];
  float bot_part[NSLICE][NSAMP][PERCLS];
};

// ---------------- prep: cls/within + class-grouped sample order ----------------
__global__ __launch_bounds__(256) void prep_kernel(const int* __restrict__ target,
                                                   Ws* __restrict__ ws) {
  __shared__ int cnt[NCLS];
  __shared__ int cur[NCLS];
  __shared__ int sc[256];
  int tid = threadIdx.x;
  for (int c = tid; c < NCLS; c += 256) cnt[c] = 0;
  __syncthreads();
  for (int n = tid; n < NSAMP; n += 256) {
    int t = target[n];
    int c = t / PERCLS;
    ws->cls[n] = c;
    ws->within[n] = t - c * PERCLS;
    atomicAdd(&cnt[c], 1);
  }
  __syncthreads();
  int v = (tid < NCLS) ? cnt[tid] : 0;
  sc[tid] = v;
  __syncthreads();
  for (int off = 1; off < 256; off <<= 1) {
    int a = (tid >= off) ? sc[tid - off] : 0;
    __syncthreads();
    sc[tid] += a;
    __syncthreads();
  }
  if (tid < NCLS) {
    int excl = sc[tid] - cnt[tid];
    ws->offsets[tid] = excl;
    cur[tid] = excl;
  }
  if (tid == 0) ws->offsets[NCLS] = NSAMP;
  __syncthreads();
  for (int n = tid; n < NSAMP; n += 256) {
    int c = ws->cls[n];
    int pos = atomicAdd(&cur[c], 1);
    ws->order[pos] = n;
  }
}

// ---------------- partial: streamed-weight, reg-double-buffered ----------------
// block = 2 k-groups x 128 threads (112 active x 2 cols). Block spans 256 k;
// the two k-groups' partials are merged in-block (LDS exchange) -> 4 slices.
__global__ __launch_bounds__(256, 5) void partial_kernel(const float* __restrict__ x,
                                                         const float* __restrict__ tw,
                                                         const float* __restrict__ bw,
                                                         Ws* __restrict__ ws) {
  __shared__ float xs[2][CH][KSL];   // 16 KB; reused as exchange buffer
  const int tid = threadIdx.x;
  const int kg = tid >> 7;           // 0/1 (wave-uniform)
  const int ct = tid & 127;          // col-thread; active if < 112
  const int bid = blockIdx.x;

  const bool is_top = bid < TOPBLKS;
  int n0 = 0, c = 0, bs, start = 0, K = CH;
  if (is_top) {
    bs = bid & 3;
    n0 = (bid >> 2) * CH;
  } else {
    int b = bid - TOPBLKS;
    bs = b & 3;
    c = b >> 2;
    start = ws->offsets[c];
    K = ws->offsets[c + 1] - start;
    if (K == 0) return;
  }
  const int kbase = bs * (2 * KSL) + kg * KSL;   // this k-group's k origin
  const float* Wbase = is_top ? (tw + (size_t)kbase * NCLS)
                              : (bw + (size_t)c * (DIM * PERCLS) + (size_t)kbase * PERCLS);
  const float2* W2 = (const float2*)Wbase + ct;  // cols (2ct, 2ct+1)

  for (int chunk = 0; chunk < K; chunk += CH) {
    const int S = min(CH, K - chunk);
    __syncthreads();   // protect xs (stage target / exchange buffer) from prior readers

    // stage x: 1024 float4 (16 KB), 4 per thread, coalesced 128B rows
#pragma unroll
    for (int pass = 0; pass < 4; ++pass) {
      int i = tid + pass * 256;
      int skg = i >> 9;
      int ss = (i >> 5) & 15;
      int q = i & 31;
      int n;
      if (is_top) n = n0 + ss;
      else        n = ws->order[start + min(chunk + ss, K - 1)];
      ((float4*)xs)[i] = *(const float4*)(x + (size_t)n * DIM + bs * (2 * KSL) + skg * KSL + q * 4);
    }
    __syncthreads();

    float2 acc[CH];
#pragma unroll
    for (int s = 0; s < CH; ++s) acc[s] = make_float2(0.f, 0.f);

    if (ct < 112) {
      const float2* Wp = W2;
      float2 wa[8], wb[8];
#pragma unroll
      for (int j = 0; j < 8; ++j) wa[j] = Wp[j * 112];
      Wp += 8 * 112;
#pragma unroll
      for (int g = 0; g < 8; ++g) {
        // prefetch next 8-k group into wb while FMAing wa
#pragma unroll
        for (int j = 0; j < 8; ++j) wb[j] = Wp[j * 112];
        Wp += 8 * 112;
#pragma unroll
        for (int s = 0; s < CH; ++s) {
          float xv[8];
          *(float4*)&xv[0] = *(const float4*)&xs[kg][s][g * 16];
          *(float4*)&xv[4] = *(const float4*)&xs[kg][s][g * 16 + 4];
#pragma unroll
          for (int j = 0; j < 8; ++j) {
            acc[s].x = fmaf(xv[j], wa[j].x, acc[s].x);
            acc[s].y = fmaf(xv[j], wa[j].y, acc[s].y);
          }
        }
        if (g < 7) {
#pragma unroll
          for (int j = 0; j < 8; ++j) wa[j] = Wp[j * 112];
          Wp += 8 * 112;
        }
#pragma unroll
        for (int s = 0; s < CH; ++s) {
          float xv[8];
          *(float4*)&xv[0] = *(const float4*)&xs[kg][s][g * 16 + 8];
          *(float4*)&xv[4] = *(const float4*)&xs[kg][s][g * 16 + 12];
#pragma unroll
          for (int j = 0; j < 8; ++j) {
            acc[s].x = fmaf(xv[j], wb[j].x, acc[s].x);
            acc[s].y = fmaf(xv[j], wb[j].y, acc[s].y);
          }
        }
      }
    }

    // merge the two k-groups' partials (reuse xs as exchange buffer)
    float2* red = (float2*)xs;     // 112*16 float2 = 14 KB
    __syncthreads();               // all xs reads done
    if (kg == 1 && ct < 112) {
#pragma unroll
      for (int s = 0; s < CH; ++s) red[s * 112 + ct] = acc[s];
    }
    __syncthreads();
    if (kg == 0 && ct < 112) {
#pragma unroll
      for (int s = 0; s < CH; ++s) {
        float2 o = red[s * 112 + ct];
        acc[s].x += o.x;
        acc[s].y += o.y;
      }
      if (is_top) {
#pragma unroll
        for (int s = 0; s < CH; ++s)
          *(float2*)&ws->top_part[bs][n0 + s][ct * 2] = acc[s];
      } else {
        for (int s = 0; s < S; ++s) {
          int n = ws->order[start + chunk + s];
          *(float2*)&ws->bot_part[bs][n][ct * 2] = acc[s];
        }
      }
    }
  }
}

// ---------------- final: reduce partials + both softmaxes + product -----------
__global__ __launch_bounds__(256) void final_kernel(const float* __restrict__ tb,
                                                    const float* __restrict__ bb,
                                                    const Ws* __restrict__ ws,
                                                    float* __restrict__ out) {
  __shared__ float lt[8][NCLS];
  __shared__ float lb[8][NCLS];
  const int tid = threadIdx.x;
  const int n0 = blockIdx.x * 8;
  const int p = tid;

  if (p < NCLS) {
    float tbias = tb[p];
#pragma unroll
    for (int s = 0; s < 8; ++s) {
      int n = n0 + s;
      int c = ws->cls[n];
      float t = tbias;
      float b = bb[(size_t)c * PERCLS + p];
#pragma unroll
      for (int dc = 0; dc < NSLICE; ++dc) t += ws->top_part[dc][n][p];
#pragma unroll
      for (int dc = 0; dc < NSLICE; ++dc) b += ws->bot_part[dc][n][p];
      lt[s][p] = t;
      lb[s][p] = b;
    }
  }
  __syncthreads();

  const int wv = tid >> 6, lane = tid & 63;
  for (int s = wv * 2; s < wv * 2 + 2; ++s) {
    const int n = n0 + s;
    float v[4], mx = -INFINITY;
#pragma unroll
    for (int j = 0; j < 4; ++j) {
      int pp = lane + 64 * j;
      v[j] = (pp < NCLS) ? lt[s][pp] : -INFINITY;
      mx = fmaxf(mx, v[j]);
    }
#pragma unroll
    for (int m = 32; m >= 1; m >>= 1) mx = fmaxf(mx, __shfl_xor(mx, m));
    float sum = 0.f;
#pragma unroll
    for (int j = 0; j < 4; ++j) {
      int pp = lane + 64 * j;
      if (pp < NCLS) sum += expf(v[j] - mx);
    }
#pragma unroll
    for (int m = 32; m >= 1; m >>= 1) sum += __shfl_xor(sum, m);
    float pt = expf(lt[s][ws->cls[n]] - mx) / sum;

    float mb = -INFINITY;
#pragma unroll
    for (int j = 0; j < 4; ++j) {
      int pp = lane + 64 * j;
      v[j] = (pp < NCLS) ? lb[s][pp] : -INFINITY;
      mb = fmaxf(mb, v[j]);
    }
#pragma unroll
    for (int m = 32; m >= 1; m >>= 1) mb = fmaxf(mb, __shfl_xor(mb, m));
    float sb = 0.f;
#pragma unroll
    for (int j = 0; j < 4; ++j) {
      int pp = lane + 64 * j;
      if (pp < NCLS) sb += expf(v[j] - mb);
    }
#pragma unroll
    for (int m = 32; m >= 1; m >>= 1) sb += __shfl_xor(sb, m);
    float pb = expf(lb[s][ws->within[n]] - mb) / sb;

    if (lane == 0) out[n] = pt * pb;
  }
}

extern "C" void kernel_launch(void* const* d_in, const int* in_sizes, int n_in,
                              void* d_out, int out_size, void* d_ws, size_t ws_size,
                              hipStream_t stream) {
  const float* x  = (const float*)d_in[0];
  const int* tgt  = (const int*)d_in[1];
  const float* tw = (const float*)d_in[2];
  const float* tb = (const float*)d_in[3];
  const float* bw = (const float*)d_in[4];
  const float* bb = (const float*)d_in[5];
  float* out = (float*)d_out;
  Ws* ws = (Ws*)d_ws;

  prep_kernel<<<1, 256, 0, stream>>>(tgt, ws);
  partial_kernel<<<TOPBLKS + BOTBLKS, 256, 0, stream>>>(x, tw, bw, ws);
  final_kernel<<<NSAMP / 8, 256, 0, stream>>>(tb, bb, ws, out);
}

// Round 6
// 88.797 us; speedup vs baseline: 6.3613x; 6.3613x over previous
//
#include <hip/hip_runtime.h>

#define NSAMP 2048
#define DIM 1024
#define NCLS 224
#define PERCLS 224
#define CH 16
#define KSL 128                    // k per k-group; block spans 2*KSL = 256 k
#define NSLICE 4
#define TOPBLKS ((NSAMP / CH) * NSLICE)   // 512
#define BOTBLKS (NCLS * NSLICE)           // 896

struct Ws {
  int cls[NSAMP];
  int within[NSAMP];
  int order[NSAMP];
  int offsets[NCLS + 1];
  int pad_[3];                      // 16B-align the partial arrays
  float top_part[NSLICE][NSAMP][NCLS];
  float bot_part[NSLICE][NSAMP][PERCLS];
};

// ---------------- prep: cls/within + class-grouped sample order ----------------
__global__ __launch_bounds__(256) void prep_kernel(const int* __restrict__ target,
                                                   Ws* __restrict__ ws) {
  __shared__ int cnt[NCLS];
  __shared__ int cur[NCLS];
  __shared__ int sc[256];
  int tid = threadIdx.x;
  for (int c = tid; c < NCLS; c += 256) cnt[c] = 0;
  __syncthreads();
  for (int n = tid; n < NSAMP; n += 256) {
    int t = target[n];
    int c = t / PERCLS;
    ws->cls[n] = c;
    ws->within[n] = t - c * PERCLS;
    atomicAdd(&cnt[c], 1);
  }
  __syncthreads();
  int v = (tid < NCLS) ? cnt[tid] : 0;
  sc[tid] = v;
  __syncthreads();
  for (int off = 1; off < 256; off <<= 1) {
    int a = (tid >= off) ? sc[tid - off] : 0;
    __syncthreads();
    sc[tid] += a;
    __syncthreads();
  }
  if (tid < NCLS) {
    int excl = sc[tid] - cnt[tid];
    ws->offsets[tid] = excl;
    cur[tid] = excl;
  }
  if (tid == 0) ws->offsets[NCLS] = NSAMP;
  __syncthreads();
  for (int n = tid; n < NSAMP; n += 256) {
    int c = ws->cls[n];
    int pos = atomicAdd(&cur[c], 1);
    ws->order[pos] = n;
  }
}

// ---------------- partial: 8 samples x 4 cols per thread, streamed weights ----
// waves: (kg, sg); lanes 0..55 = col-group (4 cols each). Per 4-k group:
// 4 coalesced float4 weight loads + 8 broadcast b128 x reads + 128 FMAs.
__global__ __launch_bounds__(256) void partial_kernel(const float* __restrict__ x,
                                                      const float* __restrict__ tw,
                                                      const float* __restrict__ bw,
                                                      Ws* __restrict__ ws) {
  __shared__ float xs[2][CH][KSL];   // 16 KB; reused as merge buffer
  const int tid = threadIdx.x;
  const int lane = tid & 63;
  const int wave = tid >> 6;
  const int kg = wave >> 1;          // k-group 0/1 (wave-uniform)
  const int sg = wave & 1;           // sample-group: samples sg*8..sg*8+7
  const int bid = blockIdx.x;

  const bool is_top = bid < TOPBLKS;
  int n0 = 0, c = 0, bs, start = 0, K = CH;
  if (is_top) {
    bs = bid & 3;
    n0 = (bid >> 2) * CH;
  } else {
    int b = bid - TOPBLKS;
    bs = b & 3;
    c = b >> 2;
    start = ws->offsets[c];
    K = ws->offsets[c + 1] - start;
    if (K == 0) return;
  }
  const int kbase = bs * (2 * KSL) + kg * KSL;
  const float* Wbase = is_top ? (tw + (size_t)kbase * NCLS)
                              : (bw + (size_t)c * (DIM * PERCLS) + (size_t)kbase * PERCLS);
  const float4* W4 = (const float4*)Wbase + lane;          // cols [lane*4, lane*4+4)
  const float4* xb = (const float4*)xs + kg * 512 + sg * 256;  // [sample][32 float4]
  float4* red4 = (float4*)xs;                               // merge view [16][56]

#define FMA4(A, XQ, W0, W1, W2, W3)                                   \
  A.x = fmaf(XQ.x, W0.x, A.x); A.y = fmaf(XQ.x, W0.y, A.y);           \
  A.z = fmaf(XQ.x, W0.z, A.z); A.w = fmaf(XQ.x, W0.w, A.w);           \
  A.x = fmaf(XQ.y, W1.x, A.x); A.y = fmaf(XQ.y, W1.y, A.y);           \
  A.z = fmaf(XQ.y, W1.z, A.z); A.w = fmaf(XQ.y, W1.w, A.w);           \
  A.x = fmaf(XQ.z, W2.x, A.x); A.y = fmaf(XQ.z, W2.y, A.y);           \
  A.z = fmaf(XQ.z, W2.z, A.z); A.w = fmaf(XQ.z, W2.w, A.w);           \
  A.x = fmaf(XQ.w, W3.x, A.x); A.y = fmaf(XQ.w, W3.y, A.y);           \
  A.z = fmaf(XQ.w, W3.z, A.z); A.w = fmaf(XQ.w, W3.w, A.w)

#define COMPUTE(W0, W1, W2, W3, G)                                    \
  { _Pragma("unroll")                                                 \
    for (int s = 0; s < 8; ++s) {                                     \
      float4 xq = xb[s * 32 + (G)];                                   \
      FMA4(acc[s], xq, W0, W1, W2, W3);                               \
    } }

  for (int chunk = 0; chunk < K; chunk += CH) {
    const int S = min(CH, K - chunk);
    __syncthreads();   // xs free (stage target / previous merge reads done)

    // stage x: 1024 float4 (16 KB), 4 per thread, coalesced
#pragma unroll
    for (int pass = 0; pass < 4; ++pass) {
      int i = tid + pass * 256;
      int kgx = i >> 9;
      int ss = (i >> 5) & 15;
      int q = i & 31;
      int n;
      if (is_top) n = n0 + ss;
      else        n = ws->order[start + min(chunk + ss, K - 1)];
      ((float4*)xs)[i] =
          *(const float4*)(x + (size_t)n * DIM + bs * (2 * KSL) + kgx * KSL + q * 4);
    }
    __syncthreads();

    float4 acc[8];
#pragma unroll
    for (int s = 0; s < 8; ++s) acc[s] = make_float4(0.f, 0.f, 0.f, 0.f);

    if (lane < 56) {
      const float4* Wp = W4;
      float4 wa0, wa1, wa2, wa3, wb0, wb1, wb2, wb3;
      wa0 = Wp[0]; wa1 = Wp[56]; wa2 = Wp[112]; wa3 = Wp[168]; Wp += 224;
#pragma unroll 5
      for (int gp = 0; gp < 15; ++gp) {
        wb0 = Wp[0]; wb1 = Wp[56]; wb2 = Wp[112]; wb3 = Wp[168]; Wp += 224;
        COMPUTE(wa0, wa1, wa2, wa3, 2 * gp);
        wa0 = Wp[0]; wa1 = Wp[56]; wa2 = Wp[112]; wa3 = Wp[168]; Wp += 224;
        COMPUTE(wb0, wb1, wb2, wb3, 2 * gp + 1);
      }
      wb0 = Wp[0]; wb1 = Wp[56]; wb2 = Wp[112]; wb3 = Wp[168];
      COMPUTE(wa0, wa1, wa2, wa3, 30);
      COMPUTE(wb0, wb1, wb2, wb3, 31);
    }

    // merge kg=1 into kg=0 via LDS (reuse xs), then write out
    __syncthreads();   // all xs compute reads done
    if (kg == 1 && lane < 56) {
#pragma unroll
      for (int s = 0; s < 8; ++s) red4[(sg * 8 + s) * 56 + lane] = acc[s];
    }
    __syncthreads();
    if (kg == 0 && lane < 56) {
      if (is_top) {
#pragma unroll
        for (int s = 0; s < 8; ++s) {
          float4 o = red4[(sg * 8 + s) * 56 + lane];
          acc[s].x += o.x; acc[s].y += o.y; acc[s].z += o.z; acc[s].w += o.w;
          *(float4*)&ws->top_part[bs][n0 + sg * 8 + s][lane * 4] = acc[s];
        }
      } else {
#pragma unroll
        for (int s = 0; s < 8; ++s) {
          int sl = sg * 8 + s;
          if (sl < S) {
            float4 o = red4[sl * 56 + lane];
            acc[s].x += o.x; acc[s].y += o.y; acc[s].z += o.z; acc[s].w += o.w;
            int n = ws->order[start + chunk + sl];
            *(float4*)&ws->bot_part[bs][n][lane * 4] = acc[s];
          }
        }
      }
    }
  }
#undef COMPUTE
#undef FMA4
}

// ---------------- final: reduce partials + both softmaxes + product -----------
__global__ __launch_bounds__(256) void final_kernel(const float* __restrict__ tb,
                                                    const float* __restrict__ bb,
                                                    const Ws* __restrict__ ws,
                                                    float* __restrict__ out) {
  __shared__ float lt[8][NCLS];
  __shared__ float lb[8][NCLS];
  const int tid = threadIdx.x;
  const int n0 = blockIdx.x * 8;
  const int p = tid;

  if (p < NCLS) {
    float tbias = tb[p];
#pragma unroll
    for (int s = 0; s < 8; ++s) {
      int n = n0 + s;
      int c = ws->cls[n];
      float t = tbias;
      float b = bb[(size_t)c * PERCLS + p];
#pragma unroll
      for (int dc = 0; dc < NSLICE; ++dc) t += ws->top_part[dc][n][p];
#pragma unroll
      for (int dc = 0; dc < NSLICE; ++dc) b += ws->bot_part[dc][n][p];
      lt[s][p] = t;
      lb[s][p] = b;
    }
  }
  __syncthreads();

  const int wv = tid >> 6, lane = tid & 63;
  for (int s = wv * 2; s < wv * 2 + 2; ++s) {
    const int n = n0 + s;
    float v[4], mx = -INFINITY;
#pragma unroll
    for (int j = 0; j < 4; ++j) {
      int pp = lane + 64 * j;
      v[j] = (pp < NCLS) ? lt[s][pp] : -INFINITY;
      mx = fmaxf(mx, v[j]);
    }
#pragma unroll
    for (int m = 32; m >= 1; m >>= 1) mx = fmaxf(mx, __shfl_xor(mx, m));
    float sum = 0.f;
#pragma unroll
    for (int j = 0; j < 4; ++j) {
      int pp = lane + 64 * j;
      if (pp < NCLS) sum += expf(v[j] - mx);
    }
#pragma unroll
    for (int m = 32; m >= 1; m >>= 1) sum += __shfl_xor(sum, m);
    float pt = expf(lt[s][ws->cls[n]] - mx) / sum;

    float mb = -INFINITY;
#pragma unroll
    for (int j = 0; j < 4; ++j) {
      int pp = lane + 64 * j;
      v[j] = (pp < NCLS) ? lb[s][pp] : -INFINITY;
      mb = fmaxf(mb, v[j]);
    }
#pragma unroll
    for (int m = 32; m >= 1; m >>= 1) mb = fmaxf(mb, __shfl_xor(mb, m));
    float sb = 0.f;
#pragma unroll
    for (int j = 0; j < 4; ++j) {
      int pp = lane + 64 * j;
      if (pp < NCLS) sb += expf(v[j] - mb);
    }
#pragma unroll
    for (int m = 32; m >= 1; m >>= 1) sb += __shfl_xor(sb, m);
    float pb = expf(lb[s][ws->within[n]] - mb) / sb;

    if (lane == 0) out[n] = pt * pb;
  }
}

extern "C" void kernel_launch(void* const* d_in, const int* in_sizes, int n_in,
                              void* d_out, int out_size, void* d_ws, size_t ws_size,
                              hipStream_t stream) {
  const float* x  = (const float*)d_in[0];
  const int* tgt  = (const int*)d_in[1];
  const float* tw = (const float*)d_in[2];
  const float* tb = (const float*)d_in[3];
  const float* bw = (const float*)d_in[4];
  const float* bb = (const float*)d_in[5];
  float* out = (float*)d_out;
  Ws* ws = (Ws*)d_ws;

  prep_kernel<<<1, 256, 0, stream>>>(tgt, ws);
  partial_kernel<<<TOPBLKS + BOTBLKS, 256, 0, stream>>>(x, tw, bw, ws);
  final_kernel<<<NSAMP / 8, 256, 0, stream>>>(tb, bb, ws, out);
}